// Round 5
// baseline (602.306 us; speedup 1.0000x reference)
//
#include <hip/hip_runtime.h>

typedef __attribute__((ext_vector_type(8))) short short8;   // 8 bf16
typedef __attribute__((ext_vector_type(4))) float f32x4;

__device__ inline ushort f2bf(float f) {
    union { float f; unsigned u; } v{f};
    unsigned r = v.u + 0x7FFF + ((v.u >> 16) & 1);
    return (ushort)(r >> 16);
}

// ---------------------------------------------------------------------------
// sen1/sen2 f32 [8192][300] -> Senb bf16 [16384][320] (zero-padded) and
// Xcat bf16 [16384][608]: cols 0..299 = sen, cols 600..607 = 0.
// (cols 300..599 are filled by the combine kernel.)
// ---------------------------------------------------------------------------
__global__ __launch_bounds__(256) void convert_inputs_kernel(
    const float* __restrict__ sen1, const float* __restrict__ sen2,
    ushort* __restrict__ Senb, ushort* __restrict__ Xcat)
{
    const int row = blockIdx.x * 8 + (threadIdx.x >> 5);
    const int c0 = threadIdx.x & 31;
    const float* src = (row < 8192) ? (sen1 + (size_t)row * 300)
                                    : (sen2 + (size_t)(row - 8192) * 300);
    ushort* sb = Senb + (size_t)row * 320;
    ushort* xc = Xcat + (size_t)row * 608;
    for (int c = c0; c < 320; c += 32) {
        ushort v = (c < 300) ? f2bf(src[c]) : (ushort)0;
        sb[c] = v;
        if (c < 300) xc[c] = v;
    }
    if (c0 < 8) xc[600 + c0] = 0;
}

// ---------------------------------------------------------------------------
// W [N][K] f32 -> Wb [224][KP] bf16 zero-padded; bias -> biasp [224] f32.
// ---------------------------------------------------------------------------
__global__ __launch_bounds__(256) void convert_weights_kernel(
    const float* __restrict__ W0, const float* __restrict__ b0,
    const float* __restrict__ W1, const float* __restrict__ b1,
    const float* __restrict__ W2, const float* __restrict__ b2,
    const float* __restrict__ W3, const float* __restrict__ b3,
    ushort* __restrict__ Wb0, float* __restrict__ bp0,
    ushort* __restrict__ Wb1, float* __restrict__ bp1,
    ushort* __restrict__ Wb2, float* __restrict__ bp2,
    ushort* __restrict__ Wb3, float* __restrict__ bp3)
{
    const int id = blockIdx.x;
    const int mat = id / 224, n = id % 224;
    const float* W; const float* b; ushort* Wb; float* bp; int N, K, KP;
    if (mat == 0)      { W = W0; b = b0; Wb = Wb0; bp = bp0; N = 200; K = 300; KP = 320; }
    else if (mat == 1) { W = W1; b = b1; Wb = Wb1; bp = bp1; N = 200; K = 200; KP = 224; }
    else if (mat == 2) { W = W2; b = b2; Wb = Wb2; bp = bp2; N = 200; K = 600; KP = 608; }
    else               { W = W3; b = b3; Wb = Wb3; bp = bp3; N = 200; K = 200; KP = 224; }
    for (int k = threadIdx.x; k < KP; k += 256)
        Wb[(size_t)n * KP + k] = (n < N && k < K) ? f2bf(W[(size_t)n * K + k]) : (ushort)0;
    if (threadIdx.x == 0) bp[n] = (n < N) ? b[n] : 0.f;
}

// ---------------------------------------------------------------------------
// sen f32 [8192][300] -> St bf16 [320][8192] transposed (pad rows zero).
// ---------------------------------------------------------------------------
__global__ __launch_bounds__(256) void transpose_bf16_kernel(
    const float* __restrict__ s1, const float* __restrict__ s2,
    ushort* __restrict__ St1, ushort* __restrict__ St2)
{
    const float* X = blockIdx.z ? s2 : s1;
    ushort* Xt = blockIdx.z ? St2 : St1;
    __shared__ float t[64][65];
    const int r0 = blockIdx.x * 64, c0 = blockIdx.y * 64;
    const int tc = threadIdx.x & 63, tr = threadIdx.x >> 6;
    for (int rr = tr; rr < 64; rr += 4) {
        int c = c0 + tc;
        t[rr][tc] = (c < 300) ? X[(size_t)(r0 + rr) * 300 + c] : 0.f;
    }
    __syncthreads();
    for (int rr = tr; rr < 64; rr += 4) {
        int oc = c0 + rr;
        if (oc < 320)
            Xt[(size_t)oc * 8192 + r0 + tc] = f2bf(t[tc][rr]);
    }
}

// ---------------------------------------------------------------------------
// Fused 2-layer MLP: Y = relu(relu(X@W1^T+b1)@W2^T+b2).
// X bf16 [M][KP1]; W1 [224][KP1]; W2 [224][224]; one wave, 16 rows/block.
// Layer-1 result goes through LDS to re-enter A-fragment layout.
// If Ybf: bf16 [M][224] out; else f32 [M][200].
// ---------------------------------------------------------------------------
__global__ __launch_bounds__(64) void mlp2_kernel(
    const ushort* __restrict__ X, int KP1,
    const ushort* __restrict__ W1, const float* __restrict__ b1,
    const ushort* __restrict__ W2, const float* __restrict__ b2,
    ushort* __restrict__ Ybf, float* __restrict__ Yf)
{
    const int r0 = blockIdx.x * 16;
    const int lane = threadIdx.x;
    const int lr = lane & 15, lg = lane >> 4;

    __shared__ __align__(16) ushort Y1[16][232];

    f32x4 a1[14];
#pragma unroll
    for (int t = 0; t < 14; ++t) a1[t] = f32x4{0.f, 0.f, 0.f, 0.f};

    const ushort* Xrow = X + (size_t)(r0 + lr) * KP1 + lg * 8;
    const ushort* W1r  = W1 + (size_t)lr * KP1 + lg * 8;
    for (int k0 = 0; k0 < KP1; k0 += 32) {
        short8 a = *(const short8*)(Xrow + k0);
#pragma unroll
        for (int t = 0; t < 14; ++t) {
            short8 bfr = *(const short8*)(W1r + (size_t)t * 16 * KP1 + k0);
            a1[t] = __builtin_amdgcn_mfma_f32_16x16x32_bf16(a, bfr, a1[t], 0, 0, 0);
        }
    }
    // C layout: col = lr (n), row = lg*4+rr -> write bf16 to LDS
#pragma unroll
    for (int t = 0; t < 14; ++t) {
        int col = t * 16 + lr;
        float bv = b1[col];
#pragma unroll
        for (int rr = 0; rr < 4; ++rr)
            Y1[lg * 4 + rr][col] = f2bf(fmaxf(a1[t][rr] + bv, 0.f));
    }
    __syncthreads();

    f32x4 a2[14];
#pragma unroll
    for (int t = 0; t < 14; ++t) a2[t] = f32x4{0.f, 0.f, 0.f, 0.f};
    const ushort* W2r = W2 + (size_t)lr * 224 + lg * 8;
    for (int k0 = 0; k0 < 224; k0 += 32) {
        short8 a = *(const short8*)&Y1[lr][lg * 8 + k0];
#pragma unroll
        for (int t = 0; t < 14; ++t) {
            short8 bfr = *(const short8*)(W2r + (size_t)t * 16 * 224 + k0);
            a2[t] = __builtin_amdgcn_mfma_f32_16x16x32_bf16(a, bfr, a2[t], 0, 0, 0);
        }
    }
#pragma unroll
    for (int t = 0; t < 14; ++t) {
        int col = t * 16 + lr;
        float bv = b2[col];
#pragma unroll
        for (int rr = 0; rr < 4; ++rr) {
            int row = r0 + lg * 4 + rr;
            float v = fmaxf(a2[t][rr] + bv, 0.f);
            if (Ybf) Ybf[(size_t)row * 224 + col] = f2bf(v);
            else if (col < 200) Yf[(size_t)row * 200 + col] = v;
        }
    }
}

// ---------------------------------------------------------------------------
// Flash attend, j-split: 64 Q-rows x 4096 j per block, 4 waves, grid 512
// (2 blocks/CU = 2 waves/SIMD). Writes raw f32 PV partials + denom partials.
// Wave w: E owns j-quarter [jb+16w,+16) x 64 i; PV owns d-quarter [80w,+80).
// ---------------------------------------------------------------------------
__global__ __launch_bounds__(256, 2) void attend_mfma_kernel(
    const ushort* __restrict__ FaFb, const ushort* __restrict__ St1,
    const ushort* __restrict__ St2, float* __restrict__ Pacc,
    float* __restrict__ Dpart)
{
    const int b = blockIdx.x;
    const int dir = b & 1;
    const int jh  = (b >> 1) & 1;
    const int it  = b >> 2;
    const ushort* A  = FaFb + (dir ? (size_t)8192 * 224 : 0);
    const ushort* B  = FaFb + (dir ? 0 : (size_t)8192 * 224);
    const ushort* St = dir ? St1 : St2;
    const int ib = it * 64;
    const int jo = jh * 4096;

    const int tid = threadIdx.x;
    const int w = tid >> 6;
    const int lane = tid & 63;
    const int lr = lane & 15, lg = lane >> 4;

    __shared__ __align__(16) ushort Pl[2][64][72];
    __shared__ float dled[4][64];

    f32x4 acc[4][5];   // [i-sub][d-tile]
#pragma unroll
    for (int s = 0; s < 4; ++s)
#pragma unroll
        for (int t = 0; t < 5; ++t) acc[s][t] = f32x4{0.f, 0.f, 0.f, 0.f};
    float dsum[4][4] = {{0.f}};

    // A fragments: rows i = ib + s*16 + lr, k-offset lg*8 + 32k (K=224)
    short8 afr[4][7];
#pragma unroll
    for (int s = 0; s < 4; ++s) {
        const ushort* Ar = A + (size_t)(ib + s * 16 + lr) * 224 + lg * 8;
#pragma unroll
        for (int k = 0; k < 7; ++k) afr[s][k] = *(const short8*)(Ar + k * 32);
    }

    // B current fragments: j-row = jo + jb + w*16 + lr
    const ushort* Brow = B + (size_t)(jo + w * 16 + lr) * 224 + lg * 8;
    short8 bfr[7];
#pragma unroll
    for (int k = 0; k < 7; ++k) bfr[k] = *(const short8*)(Brow + k * 32);

    const ushort* Sbase = St + (size_t)(w * 80 + lr) * 8192 + jo + lg * 8;

    int buf = 0;
    for (int jb = 0; jb < 4096; jb += 64, buf ^= 1) {
        // St fragments for this jb (used in PV after the barrier)
        short8 st[5][2];
#pragma unroll
        for (int t = 0; t < 5; ++t)
#pragma unroll
            for (int h = 0; h < 2; ++h)
                st[t][h] = *(const short8*)(Sbase + (size_t)t * 16 * 8192 + jb + h * 32);

        // ---- E: wave w computes E[64 i x 16 j] ----
        f32x4 e[4];
#pragma unroll
        for (int s = 0; s < 4; ++s) e[s] = f32x4{0.f, 0.f, 0.f, 0.f};
#pragma unroll
        for (int k = 0; k < 7; ++k)
#pragma unroll
            for (int s = 0; s < 4; ++s)
                e[s] = __builtin_amdgcn_mfma_f32_16x16x32_bf16(afr[s][k], bfr[k], e[s], 0, 0, 0);

        // exp (no max-sub: args ~2..5); per-lane partial denom; bf16 P -> LDS
#pragma unroll
        for (int s = 0; s < 4; ++s)
#pragma unroll
            for (int r = 0; r < 4; ++r) {
                float x = __expf(e[s][r]);
                dsum[s][r] += x;
                Pl[buf][s * 16 + lg * 4 + r][w * 16 + lr] = f2bf(x);
            }
        __syncthreads();

        // prefetch next B tile rows (used next iteration)
        if (jb + 64 < 4096) {
            const ushort* Bn = Brow + (size_t)(jo + jb + 64) * 224 - (size_t)jo * 224;
#pragma unroll
            for (int k = 0; k < 7; ++k)
                bfr[k] = *(const short8*)(Brow + (size_t)(jb + 64) * 224 + k * 32);
            (void)Bn;
        }

        // ---- PV: wave w computes O[64 i x 80 d] over these 64 j ----
#pragma unroll
        for (int h = 0; h < 2; ++h) {
            short8 pf[4];
#pragma unroll
            for (int s = 0; s < 4; ++s)
                pf[s] = *(const short8*)&Pl[buf][s * 16 + lr][h * 32 + lg * 8];
#pragma unroll
            for (int s = 0; s < 4; ++s)
#pragma unroll
                for (int t = 0; t < 5; ++t)
                    acc[s][t] = __builtin_amdgcn_mfma_f32_16x16x32_bf16(pf[s], st[t][h], acc[s][t], 0, 0, 0);
        }
        // no second barrier: next iteration writes the other P buffer
    }

    // denominator: reduce over 16 lanes (j within quarter), then across waves
#pragma unroll
    for (int m = 1; m < 16; m <<= 1)
#pragma unroll
        for (int s = 0; s < 4; ++s)
#pragma unroll
            for (int r = 0; r < 4; ++r)
                dsum[s][r] += __shfl_xor(dsum[s][r], m);
    if (lr == 0) {
#pragma unroll
        for (int s = 0; s < 4; ++s)
#pragma unroll
            for (int r = 0; r < 4; ++r)
                dled[w][s * 16 + lg * 4 + r] = dsum[s][r];
    }
    __syncthreads();

    // Dpart[jh][dir*8192 + ib + il]
    if (tid < 64) {
        float d = dled[0][tid] + dled[1][tid] + dled[2][tid] + dled[3][tid];
        Dpart[(size_t)jh * 16384 + dir * 8192 + ib + tid] = d;
    }

    // raw partials: Pacc[jh][dir*8192 + i][d]
    float* Pb = Pacc + ((size_t)jh * 16384 + dir * 8192 + ib) * 320;
#pragma unroll
    for (int t = 0; t < 5; ++t) {
        int d = w * 80 + t * 16 + lr;
#pragma unroll
        for (int s = 0; s < 4; ++s)
#pragma unroll
            for (int r = 0; r < 4; ++r)
                Pb[(size_t)(s * 16 + lg * 4 + r) * 320 + d] = acc[s][t][r];
    }
}

// ---------------------------------------------------------------------------
// combine: beta/alpha = (PaccA + PaccB) / (DA + DB) -> bf16 into Xcat[.,300+]
// ---------------------------------------------------------------------------
__global__ __launch_bounds__(256) void combine_kernel(
    const float* __restrict__ Pacc, const float* __restrict__ Dpart,
    ushort* __restrict__ Xcat)
{
    const int row = blockIdx.x * 8 + (threadIdx.x >> 5);
    const int c0 = threadIdx.x & 31;
    const float inv = 1.f / (Dpart[row] + Dpart[16384 + row]);
    const float* pa = Pacc + (size_t)row * 320;
    const float* pb = Pacc + (size_t)(16384 + row) * 320;
    ushort* xc = Xcat + (size_t)row * 608 + 300;
    for (int d = c0; d < 300; d += 32)
        xc[d] = f2bf((pa[d] + pb[d]) * inv);
}

// ---------------------------------------------------------------------------
// hsum[c] = sum_r v[r][c%200] over the half selected by c/200. c in [0,400).
// ---------------------------------------------------------------------------
__global__ __launch_bounds__(256) void colsum_kernel(
    const float* __restrict__ v, float* __restrict__ hsum)
{
    const int c = blockIdx.x;
    const float* V = v + (c < 200 ? 0 : (size_t)8192 * 200);
    const int col = c % 200;
    float s = 0.f;
    for (int r = threadIdx.x; r < 8192; r += 256)
        s += V[(size_t)r * 200 + col];
    __shared__ float red[256];
    red[threadIdx.x] = s;
    __syncthreads();
    for (int off = 128; off > 0; off >>= 1) {
        if (threadIdx.x < off) red[threadIdx.x] += red[threadIdx.x + off];
        __syncthreads();
    }
    if (threadIdx.x == 0) hsum[c] = red[0];
}

__global__ __launch_bounds__(256) void head_kernel(
    const float* __restrict__ hsum,
    const float* __restrict__ Hw1, const float* __restrict__ Hb1,
    const float* __restrict__ Hw2, const float* __restrict__ Hb2,
    float* __restrict__ out)
{
    __shared__ float hx[400];
    __shared__ float hr[200];
    __shared__ float lg[3];
    const int t = threadIdx.x;
    for (int i = t; i < 400; i += 256) hx[i] = hsum[i];
    __syncthreads();
    if (t < 200) {
        float a = Hb1[t];
        for (int k = 0; k < 400; ++k) a = fmaf(hx[k], Hw1[t * 400 + k], a);
        hr[t] = fmaxf(a, 0.f);
    }
    __syncthreads();
    if (t < 3) {
        float a = Hb2[t];
        for (int k = 0; k < 200; ++k) a = fmaf(hr[k], Hw2[t * 200 + k], a);
        lg[t] = a;
    }
    __syncthreads();
    if (t == 0) {
        float m = fmaxf(lg[0], fmaxf(lg[1], lg[2]));
        float e0 = __expf(lg[0] - m);
        float e1 = __expf(lg[1] - m);
        float e2 = __expf(lg[2] - m);
        float s = e0 + e1 + e2;
        out[0] = e0 / s;
        out[1] = e1 / s;
        out[2] = e2 / s;
    }
}

extern "C" void kernel_launch(void* const* d_in, const int* in_sizes, int n_in,
                              void* d_out, int out_size, void* d_ws, size_t ws_size,
                              hipStream_t stream)
{
    const float* sen1 = (const float*)d_in[0];
    const float* sen2 = (const float*)d_in[1];
    const float* F_w1 = (const float*)d_in[2];
    const float* F_b1 = (const float*)d_in[3];
    const float* F_w2 = (const float*)d_in[4];
    const float* F_b2 = (const float*)d_in[5];
    const float* G_w1 = (const float*)d_in[6];
    const float* G_b1 = (const float*)d_in[7];
    const float* G_w2 = (const float*)d_in[8];
    const float* G_b2 = (const float*)d_in[9];
    const float* H_w1 = (const float*)d_in[10];
    const float* H_b1 = (const float*)d_in[11];
    const float* H_w2 = (const float*)d_in[12];
    const float* H_b2 = (const float*)d_in[13];
    float* out = (float*)d_out;

    const int L = 8192;
    char* p = (char*)d_ws;
    ushort* St1  = (ushort*)p; p += (size_t)320 * L * 2;       // 5.24 MB
    ushort* St2  = (ushort*)p; p += (size_t)320 * L * 2;       // 5.24 MB
    ushort* FaFb = (ushort*)p; p += (size_t)2 * L * 224 * 2;   // 7.34 MB
    ushort* Xcat = (ushort*)p; p += (size_t)2 * L * 608 * 2;   // 19.92 MB
    ushort* WbF1 = (ushort*)p; p += (size_t)224 * 320 * 2;
    ushort* WbF2 = (ushort*)p; p += (size_t)224 * 224 * 2;
    ushort* WbG1 = (ushort*)p; p += (size_t)224 * 608 * 2;
    ushort* WbG2 = (ushort*)p; p += (size_t)224 * 224 * 2;
    float*  bpF1 = (float*)p;  p += 224 * 4;
    float*  bpF2 = (float*)p;  p += 224 * 4;
    float*  bpG1 = (float*)p;  p += 224 * 4;
    float*  bpG2 = (float*)p;  p += 224 * 4;
    float*  hsum = (float*)p;  p += 400 * 4;
    // union region U: Senb (10.5 MB, used pre-attend) / Pacc+Dpart (42.1 MB,
    // attend+combine) / v (26.2 MB, post-combine)
    ushort* Senb  = (ushort*)p;
    float*  Pacc  = (float*)p;
    float*  Dpart = (float*)(p + (size_t)2 * 16384 * 320 * 4);
    float*  v     = (float*)p;

    dim3 blk256(256);

    hipLaunchKernelGGL(convert_inputs_kernel, dim3(2 * L / 8), blk256, 0, stream,
                       sen1, sen2, Senb, Xcat);
    hipLaunchKernelGGL(transpose_bf16_kernel, dim3(L / 64, 5, 2), blk256, 0, stream,
                       sen1, sen2, St1, St2);
    hipLaunchKernelGGL(convert_weights_kernel, dim3(4 * 224), blk256, 0, stream,
                       F_w1, F_b1, F_w2, F_b2, G_w1, G_b1, G_w2, G_b2,
                       WbF1, bpF1, WbF2, bpF2, WbG1, bpG1, WbG2, bpG2);

    // F MLP fused (both sentences, M = 16384) -> FaFb bf16
    hipLaunchKernelGGL(mlp2_kernel, dim3(2 * L / 16), dim3(64), 0, stream,
                       Senb, 320, WbF1, bpF1, WbF2, bpF2, FaFb, (float*)nullptr);

    // flash attend, j-split partials
    hipLaunchKernelGGL(attend_mfma_kernel, dim3(512), blk256, 0, stream,
                       FaFb, St1, St2, Pacc, Dpart);
    // combine -> Xcat cols 300..599
    hipLaunchKernelGGL(combine_kernel, dim3(16384 / 8), blk256, 0, stream,
                       Pacc, Dpart, Xcat);

    // G MLP fused -> v f32
    hipLaunchKernelGGL(mlp2_kernel, dim3(2 * L / 16), dim3(64), 0, stream,
                       Xcat, 608, WbG1, bpG1, WbG2, bpG2, (ushort*)nullptr, v);

    hipLaunchKernelGGL(colsum_kernel, dim3(400), blk256, 0, stream, v, hsum);
    hipLaunchKernelGGL(head_kernel, dim3(1), blk256, 0, stream,
                       hsum, H_w1, H_b1, H_w2, H_b2, out);
}

// Round 6
// 388.726 us; speedup vs baseline: 1.5494x; 1.5494x over previous
//
#include <hip/hip_runtime.h>

typedef __attribute__((ext_vector_type(8))) short short8;   // 8 bf16
typedef __attribute__((ext_vector_type(4))) float f32x4;

__device__ inline ushort f2bf(float f) {
    union { float f; unsigned u; } v{f};
    unsigned r = v.u + 0x7FFF + ((v.u >> 16) & 1);
    return (ushort)(r >> 16);
}

// ---------------------------------------------------------------------------
// sen1/sen2 f32 [8192][300] -> Senb bf16 [16384][320] (zero-padded) and
// Xcat bf16 [16384][608]: cols 0..299 = sen, cols 600..607 = 0.
// ---------------------------------------------------------------------------
__global__ __launch_bounds__(256) void convert_inputs_kernel(
    const float* __restrict__ sen1, const float* __restrict__ sen2,
    ushort* __restrict__ Senb, ushort* __restrict__ Xcat)
{
    const int row = blockIdx.x * 8 + (threadIdx.x >> 5);
    const int c0 = threadIdx.x & 31;
    const float* src = (row < 8192) ? (sen1 + (size_t)row * 300)
                                    : (sen2 + (size_t)(row - 8192) * 300);
    ushort* sb = Senb + (size_t)row * 320;
    ushort* xc = Xcat + (size_t)row * 608;
    for (int c = c0; c < 320; c += 32) {
        ushort v = (c < 300) ? f2bf(src[c]) : (ushort)0;
        sb[c] = v;
        if (c < 300) xc[c] = v;
    }
    if (c0 < 8) xc[600 + c0] = 0;
}

// ---------------------------------------------------------------------------
// W [N][K] f32 -> Wb [224][KP] bf16 zero-padded; bias -> biasp [224] f32.
// ---------------------------------------------------------------------------
__global__ __launch_bounds__(256) void convert_weights_kernel(
    const float* __restrict__ W0, const float* __restrict__ b0,
    const float* __restrict__ W1, const float* __restrict__ b1,
    const float* __restrict__ W2, const float* __restrict__ b2,
    const float* __restrict__ W3, const float* __restrict__ b3,
    ushort* __restrict__ Wb0, float* __restrict__ bp0,
    ushort* __restrict__ Wb1, float* __restrict__ bp1,
    ushort* __restrict__ Wb2, float* __restrict__ bp2,
    ushort* __restrict__ Wb3, float* __restrict__ bp3)
{
    const int id = blockIdx.x;
    const int mat = id / 224, n = id % 224;
    const float* W; const float* b; ushort* Wb; float* bp; int N, K, KP;
    if (mat == 0)      { W = W0; b = b0; Wb = Wb0; bp = bp0; N = 200; K = 300; KP = 320; }
    else if (mat == 1) { W = W1; b = b1; Wb = Wb1; bp = bp1; N = 200; K = 200; KP = 224; }
    else if (mat == 2) { W = W2; b = b2; Wb = Wb2; bp = bp2; N = 200; K = 600; KP = 608; }
    else               { W = W3; b = b3; Wb = Wb3; bp = bp3; N = 200; K = 200; KP = 224; }
    for (int k = threadIdx.x; k < KP; k += 256)
        Wb[(size_t)n * KP + k] = (n < N && k < K) ? f2bf(W[(size_t)n * K + k]) : (ushort)0;
    if (threadIdx.x == 0) bp[n] = (n < N) ? b[n] : 0.f;
}

// ---------------------------------------------------------------------------
// sen f32 [8192][300] -> St bf16 [320][8192] transposed (pad rows zero).
// ---------------------------------------------------------------------------
__global__ __launch_bounds__(256) void transpose_bf16_kernel(
    const float* __restrict__ s1, const float* __restrict__ s2,
    ushort* __restrict__ St1, ushort* __restrict__ St2)
{
    const float* X = blockIdx.z ? s2 : s1;
    ushort* Xt = blockIdx.z ? St2 : St1;
    __shared__ float t[64][65];
    const int r0 = blockIdx.x * 64, c0 = blockIdx.y * 64;
    const int tc = threadIdx.x & 63, tr = threadIdx.x >> 6;
    for (int rr = tr; rr < 64; rr += 4) {
        int c = c0 + tc;
        t[rr][tc] = (c < 300) ? X[(size_t)(r0 + rr) * 300 + c] : 0.f;
    }
    __syncthreads();
    for (int rr = tr; rr < 64; rr += 4) {
        int oc = c0 + rr;
        if (oc < 320)
            Xt[(size_t)oc * 8192 + r0 + tc] = f2bf(t[tc][rr]);
    }
}

// ---------------------------------------------------------------------------
// Fused 2-layer MLP: Y = relu(relu(X@W1^T+b1)@W2^T+b2).
// X bf16 [M][KP1]; W1 [224][KP1]; W2 [224][224]; one wave, 16 rows/block.
// ---------------------------------------------------------------------------
__global__ __launch_bounds__(64) void mlp2_kernel(
    const ushort* __restrict__ X, int KP1,
    const ushort* __restrict__ W1, const float* __restrict__ b1,
    const ushort* __restrict__ W2, const float* __restrict__ b2,
    ushort* __restrict__ Ybf, float* __restrict__ Yf)
{
    const int r0 = blockIdx.x * 16;
    const int lane = threadIdx.x;
    const int lr = lane & 15, lg = lane >> 4;

    __shared__ __align__(16) ushort Y1[16][232];

    f32x4 a1[14];
#pragma unroll
    for (int t = 0; t < 14; ++t) a1[t] = f32x4{0.f, 0.f, 0.f, 0.f};

    const ushort* Xrow = X + (size_t)(r0 + lr) * KP1 + lg * 8;
    const ushort* W1r  = W1 + (size_t)lr * KP1 + lg * 8;
    for (int k0 = 0; k0 < KP1; k0 += 32) {
        short8 a = *(const short8*)(Xrow + k0);
#pragma unroll
        for (int t = 0; t < 14; ++t) {
            short8 bfr = *(const short8*)(W1r + (size_t)t * 16 * KP1 + k0);
            a1[t] = __builtin_amdgcn_mfma_f32_16x16x32_bf16(a, bfr, a1[t], 0, 0, 0);
        }
    }
#pragma unroll
    for (int t = 0; t < 14; ++t) {
        int col = t * 16 + lr;
        float bv = b1[col];
#pragma unroll
        for (int rr = 0; rr < 4; ++rr)
            Y1[lg * 4 + rr][col] = f2bf(fmaxf(a1[t][rr] + bv, 0.f));
    }
    __syncthreads();

    f32x4 a2[14];
#pragma unroll
    for (int t = 0; t < 14; ++t) a2[t] = f32x4{0.f, 0.f, 0.f, 0.f};
    const ushort* W2r = W2 + (size_t)lr * 224 + lg * 8;
    for (int k0 = 0; k0 < 224; k0 += 32) {
        short8 a = *(const short8*)&Y1[lr][lg * 8 + k0];
#pragma unroll
        for (int t = 0; t < 14; ++t) {
            short8 bfr = *(const short8*)(W2r + (size_t)t * 16 * 224 + k0);
            a2[t] = __builtin_amdgcn_mfma_f32_16x16x32_bf16(a, bfr, a2[t], 0, 0, 0);
        }
    }
#pragma unroll
    for (int t = 0; t < 14; ++t) {
        int col = t * 16 + lr;
        float bv = b2[col];
#pragma unroll
        for (int rr = 0; rr < 4; ++rr) {
            int row = r0 + lg * 4 + rr;
            float v = fmaxf(a2[t][rr] + bv, 0.f);
            if (Ybf) Ybf[(size_t)row * 224 + col] = f2bf(v);
            else if (col < 200) Yf[(size_t)row * 200 + col] = v;
        }
    }
}

// ---------------------------------------------------------------------------
// Flash attend, j-split: 64 Q-rows x 4096 j per block, 4 waves, grid 512
// (2 blocks/CU from the VGPR pool: ~172 regs x 2 < 512 -> 2 waves/SIMD).
// NOTE: no min-occupancy launch_bounds — a (256,2) hint capped VGPRs at 128
// and spilled (R5: FETCH 38->287 MB, dur 237->476 us). Registers must float.
// ---------------------------------------------------------------------------
__global__ __launch_bounds__(256, 1) void attend_mfma_kernel(
    const ushort* __restrict__ FaFb, const ushort* __restrict__ St1,
    const ushort* __restrict__ St2, float* __restrict__ Pacc,
    float* __restrict__ Dpart)
{
    const int b = blockIdx.x;
    const int dir = b & 1;
    const int jh  = (b >> 1) & 1;
    const int it  = b >> 2;
    const ushort* A  = FaFb + (dir ? (size_t)8192 * 224 : 0);
    const ushort* B  = FaFb + (dir ? 0 : (size_t)8192 * 224);
    const ushort* St = dir ? St1 : St2;
    const int ib = it * 64;
    const int jo = jh * 4096;

    const int tid = threadIdx.x;
    const int w = tid >> 6;
    const int lane = tid & 63;
    const int lr = lane & 15, lg = lane >> 4;

    __shared__ __align__(16) ushort Pl[2][64][72];
    __shared__ float dled[4][64];

    f32x4 acc[4][5];   // [i-sub][d-tile]
#pragma unroll
    for (int s = 0; s < 4; ++s)
#pragma unroll
        for (int t = 0; t < 5; ++t) acc[s][t] = f32x4{0.f, 0.f, 0.f, 0.f};
    float dsum[4][4] = {{0.f}};

    // A fragments: rows i = ib + s*16 + lr, k-offset lg*8 + 32k (K=224)
    short8 afr[4][7];
#pragma unroll
    for (int s = 0; s < 4; ++s) {
        const ushort* Ar = A + (size_t)(ib + s * 16 + lr) * 224 + lg * 8;
#pragma unroll
        for (int k = 0; k < 7; ++k) afr[s][k] = *(const short8*)(Ar + k * 32);
    }

    // B current fragments: j-row = jo + jb + w*16 + lr
    const ushort* Brow = B + (size_t)(jo + w * 16 + lr) * 224 + lg * 8;
    short8 bfr[7];
#pragma unroll
    for (int k = 0; k < 7; ++k) bfr[k] = *(const short8*)(Brow + k * 32);

    const ushort* Sbase = St + (size_t)(w * 80 + lr) * 8192 + jo + lg * 8;

    int buf = 0;
    for (int jb = 0; jb < 4096; jb += 64, buf ^= 1) {
        // St fragments for this jb (consumed in PV after the barrier)
        short8 st[5][2];
#pragma unroll
        for (int t = 0; t < 5; ++t)
#pragma unroll
            for (int h = 0; h < 2; ++h)
                st[t][h] = *(const short8*)(Sbase + (size_t)t * 16 * 8192 + jb + h * 32);

        // ---- E: wave w computes E[64 i x 16 j] ----
        f32x4 e[4];
#pragma unroll
        for (int s = 0; s < 4; ++s) e[s] = f32x4{0.f, 0.f, 0.f, 0.f};
#pragma unroll
        for (int k = 0; k < 7; ++k)
#pragma unroll
            for (int s = 0; s < 4; ++s)
                e[s] = __builtin_amdgcn_mfma_f32_16x16x32_bf16(afr[s][k], bfr[k], e[s], 0, 0, 0);

        // exp (no max-sub: args ~2..5); per-lane partial denom; bf16 P -> LDS
#pragma unroll
        for (int s = 0; s < 4; ++s)
#pragma unroll
            for (int r = 0; r < 4; ++r) {
                float x = __expf(e[s][r]);
                dsum[s][r] += x;
                Pl[buf][s * 16 + lg * 4 + r][w * 16 + lr] = f2bf(x);
            }
        __syncthreads();

        // prefetch next B tile rows (used next iteration)
        if (jb + 64 < 4096) {
#pragma unroll
            for (int k = 0; k < 7; ++k)
                bfr[k] = *(const short8*)(Brow + (size_t)(jb + 64) * 224 + k * 32);
        }

        // ---- PV: wave w computes O[64 i x 80 d] over these 64 j ----
#pragma unroll
        for (int h = 0; h < 2; ++h) {
            short8 pf[4];
#pragma unroll
            for (int s = 0; s < 4; ++s)
                pf[s] = *(const short8*)&Pl[buf][s * 16 + lr][h * 32 + lg * 8];
#pragma unroll
            for (int s = 0; s < 4; ++s)
#pragma unroll
                for (int t = 0; t < 5; ++t)
                    acc[s][t] = __builtin_amdgcn_mfma_f32_16x16x32_bf16(pf[s], st[t][h], acc[s][t], 0, 0, 0);
        }
        // no second barrier: next iteration writes the other P buffer
    }

    // denominator: reduce over 16 lanes (j within quarter), then across waves
#pragma unroll
    for (int m = 1; m < 16; m <<= 1)
#pragma unroll
        for (int s = 0; s < 4; ++s)
#pragma unroll
            for (int r = 0; r < 4; ++r)
                dsum[s][r] += __shfl_xor(dsum[s][r], m);
    if (lr == 0) {
#pragma unroll
        for (int s = 0; s < 4; ++s)
#pragma unroll
            for (int r = 0; r < 4; ++r)
                dled[w][s * 16 + lg * 4 + r] = dsum[s][r];
    }
    __syncthreads();

    // Dpart[jh][dir*8192 + ib + il]
    if (tid < 64) {
        float d = dled[0][tid] + dled[1][tid] + dled[2][tid] + dled[3][tid];
        Dpart[(size_t)jh * 16384 + dir * 8192 + ib + tid] = d;
    }

    // raw partials: Pacc[jh][dir*8192 + i][d]
    float* Pb = Pacc + ((size_t)jh * 16384 + dir * 8192 + ib) * 320;
#pragma unroll
    for (int t = 0; t < 5; ++t) {
        int d = w * 80 + t * 16 + lr;
#pragma unroll
        for (int s = 0; s < 4; ++s)
#pragma unroll
            for (int r = 0; r < 4; ++r)
                Pb[(size_t)(s * 16 + lg * 4 + r) * 320 + d] = acc[s][t][r];
    }
}

// ---------------------------------------------------------------------------
// combine: beta/alpha = (PaccA + PaccB) / (DA + DB) -> bf16 into Xcat[.,300+]
// ---------------------------------------------------------------------------
__global__ __launch_bounds__(256) void combine_kernel(
    const float* __restrict__ Pacc, const float* __restrict__ Dpart,
    ushort* __restrict__ Xcat)
{
    const int row = blockIdx.x * 8 + (threadIdx.x >> 5);
    const int c0 = threadIdx.x & 31;
    const float inv = 1.f / (Dpart[row] + Dpart[16384 + row]);
    const float* pa = Pacc + (size_t)row * 320;
    const float* pb = Pacc + (size_t)(16384 + row) * 320;
    ushort* xc = Xcat + (size_t)row * 608 + 300;
    for (int d = c0; d < 300; d += 32)
        xc[d] = f2bf((pa[d] + pb[d]) * inv);
}

// ---------------------------------------------------------------------------
// hsum[c] = sum_r v[r][c%200] over the half selected by c/200. c in [0,400).
// ---------------------------------------------------------------------------
__global__ __launch_bounds__(256) void colsum_kernel(
    const float* __restrict__ v, float* __restrict__ hsum)
{
    const int c = blockIdx.x;
    const float* V = v + (c < 200 ? 0 : (size_t)8192 * 200);
    const int col = c % 200;
    float s = 0.f;
    for (int r = threadIdx.x; r < 8192; r += 256)
        s += V[(size_t)r * 200 + col];
    __shared__ float red[256];
    red[threadIdx.x] = s;
    __syncthreads();
    for (int off = 128; off > 0; off >>= 1) {
        if (threadIdx.x < off) red[threadIdx.x] += red[threadIdx.x + off];
        __syncthreads();
    }
    if (threadIdx.x == 0) hsum[c] = red[0];
}

__global__ __launch_bounds__(256) void head_kernel(
    const float* __restrict__ hsum,
    const float* __restrict__ Hw1, const float* __restrict__ Hb1,
    const float* __restrict__ Hw2, const float* __restrict__ Hb2,
    float* __restrict__ out)
{
    __shared__ float hx[400];
    __shared__ float hr[200];
    __shared__ float lg[3];
    const int t = threadIdx.x;
    for (int i = t; i < 400; i += 256) hx[i] = hsum[i];
    __syncthreads();
    if (t < 200) {
        float a = Hb1[t];
        for (int k = 0; k < 400; ++k) a = fmaf(hx[k], Hw1[t * 400 + k], a);
        hr[t] = fmaxf(a, 0.f);
    }
    __syncthreads();
    if (t < 3) {
        float a = Hb2[t];
        for (int k = 0; k < 200; ++k) a = fmaf(hr[k], Hw2[t * 200 + k], a);
        lg[t] = a;
    }
    __syncthreads();
    if (t == 0) {
        float m = fmaxf(lg[0], fmaxf(lg[1], lg[2]));
        float e0 = __expf(lg[0] - m);
        float e1 = __expf(lg[1] - m);
        float e2 = __expf(lg[2] - m);
        float s = e0 + e1 + e2;
        out[0] = e0 / s;
        out[1] = e1 / s;
        out[2] = e2 / s;
    }
}

extern "C" void kernel_launch(void* const* d_in, const int* in_sizes, int n_in,
                              void* d_out, int out_size, void* d_ws, size_t ws_size,
                              hipStream_t stream)
{
    const float* sen1 = (const float*)d_in[0];
    const float* sen2 = (const float*)d_in[1];
    const float* F_w1 = (const float*)d_in[2];
    const float* F_b1 = (const float*)d_in[3];
    const float* F_w2 = (const float*)d_in[4];
    const float* F_b2 = (const float*)d_in[5];
    const float* G_w1 = (const float*)d_in[6];
    const float* G_b1 = (const float*)d_in[7];
    const float* G_w2 = (const float*)d_in[8];
    const float* G_b2 = (const float*)d_in[9];
    const float* H_w1 = (const float*)d_in[10];
    const float* H_b1 = (const float*)d_in[11];
    const float* H_w2 = (const float*)d_in[12];
    const float* H_b2 = (const float*)d_in[13];
    float* out = (float*)d_out;

    const int L = 8192;
    char* p = (char*)d_ws;
    ushort* St1  = (ushort*)p; p += (size_t)320 * L * 2;       // 5.24 MB
    ushort* St2  = (ushort*)p; p += (size_t)320 * L * 2;       // 5.24 MB
    ushort* FaFb = (ushort*)p; p += (size_t)2 * L * 224 * 2;   // 7.34 MB
    ushort* Xcat = (ushort*)p; p += (size_t)2 * L * 608 * 2;   // 19.92 MB
    ushort* WbF1 = (ushort*)p; p += (size_t)224 * 320 * 2;
    ushort* WbF2 = (ushort*)p; p += (size_t)224 * 224 * 2;
    ushort* WbG1 = (ushort*)p; p += (size_t)224 * 608 * 2;
    ushort* WbG2 = (ushort*)p; p += (size_t)224 * 224 * 2;
    float*  bpF1 = (float*)p;  p += 224 * 4;
    float*  bpF2 = (float*)p;  p += 224 * 4;
    float*  bpG1 = (float*)p;  p += 224 * 4;
    float*  bpG2 = (float*)p;  p += 224 * 4;
    float*  hsum = (float*)p;  p += 400 * 4;
    // union region U: Senb (10.5 MB, pre-attend) / Pacc+Dpart (42.1 MB,
    // attend+combine) / v (26.2 MB, post-combine)
    ushort* Senb  = (ushort*)p;
    float*  Pacc  = (float*)p;
    float*  Dpart = (float*)(p + (size_t)2 * 16384 * 320 * 4);
    float*  v     = (float*)p;

    dim3 blk256(256);

    hipLaunchKernelGGL(convert_inputs_kernel, dim3(2 * L / 8), blk256, 0, stream,
                       sen1, sen2, Senb, Xcat);
    hipLaunchKernelGGL(transpose_bf16_kernel, dim3(L / 64, 5, 2), blk256, 0, stream,
                       sen1, sen2, St1, St2);
    hipLaunchKernelGGL(convert_weights_kernel, dim3(4 * 224), blk256, 0, stream,
                       F_w1, F_b1, F_w2, F_b2, G_w1, G_b1, G_w2, G_b2,
                       WbF1, bpF1, WbF2, bpF2, WbG1, bpG1, WbG2, bpG2);

    // F MLP fused (both sentences, M = 16384) -> FaFb bf16
    hipLaunchKernelGGL(mlp2_kernel, dim3(2 * L / 16), dim3(64), 0, stream,
                       Senb, 320, WbF1, bpF1, WbF2, bpF2, FaFb, (float*)nullptr);

    // flash attend, j-split partials
    hipLaunchKernelGGL(attend_mfma_kernel, dim3(512), blk256, 0, stream,
                       FaFb, St1, St2, Pacc, Dpart);
    // combine -> Xcat cols 300..599
    hipLaunchKernelGGL(combine_kernel, dim3(16384 / 8), blk256, 0, stream,
                       Pacc, Dpart, Xcat);

    // G MLP fused -> v f32
    hipLaunchKernelGGL(mlp2_kernel, dim3(2 * L / 16), dim3(64), 0, stream,
                       Xcat, 608, WbG1, bpG1, WbG2, bpG2, (ushort*)nullptr, v);

    hipLaunchKernelGGL(colsum_kernel, dim3(400), blk256, 0, stream, v, hsum);
    hipLaunchKernelGGL(head_kernel, dim3(1), blk256, 0, stream,
                       hsum, H_w1, H_b1, H_w2, H_b2, out);
}

// Round 7
// 351.893 us; speedup vs baseline: 1.7116x; 1.1047x over previous
//
#include <hip/hip_runtime.h>

typedef __attribute__((ext_vector_type(8))) short short8;   // 8 bf16
typedef __attribute__((ext_vector_type(4))) float f32x4;

__device__ inline ushort f2bf(float f) {
    union { float f; unsigned u; } v{f};
    unsigned r = v.u + 0x7FFF + ((v.u >> 16) & 1);
    return (ushort)(r >> 16);
}

// ---------------------------------------------------------------------------
// sen1/sen2 f32 [8192][300] -> Senb bf16 [16384][320] (zero-padded) and
// Xcat bf16 [16384][608]: cols 0..299 = sen, cols 600..607 = 0.
// ---------------------------------------------------------------------------
__global__ __launch_bounds__(256) void convert_inputs_kernel(
    const float* __restrict__ sen1, const float* __restrict__ sen2,
    ushort* __restrict__ Senb, ushort* __restrict__ Xcat)
{
    const int row = blockIdx.x * 8 + (threadIdx.x >> 5);
    const int c0 = threadIdx.x & 31;
    const float* src = (row < 8192) ? (sen1 + (size_t)row * 300)
                                    : (sen2 + (size_t)(row - 8192) * 300);
    ushort* sb = Senb + (size_t)row * 320;
    ushort* xc = Xcat + (size_t)row * 608;
    for (int c = c0; c < 320; c += 32) {
        ushort v = (c < 300) ? f2bf(src[c]) : (ushort)0;
        sb[c] = v;
        if (c < 300) xc[c] = v;
    }
    if (c0 < 8) xc[600 + c0] = 0;
}

// ---------------------------------------------------------------------------
// W [N][K] f32 -> Wb [224][KP] bf16 zero-padded; bias -> biasp [224] f32.
// ---------------------------------------------------------------------------
__global__ __launch_bounds__(256) void convert_weights_kernel(
    const float* __restrict__ W0, const float* __restrict__ b0,
    const float* __restrict__ W1, const float* __restrict__ b1,
    const float* __restrict__ W2, const float* __restrict__ b2,
    const float* __restrict__ W3, const float* __restrict__ b3,
    ushort* __restrict__ Wb0, float* __restrict__ bp0,
    ushort* __restrict__ Wb1, float* __restrict__ bp1,
    ushort* __restrict__ Wb2, float* __restrict__ bp2,
    ushort* __restrict__ Wb3, float* __restrict__ bp3)
{
    const int id = blockIdx.x;
    const int mat = id / 224, n = id % 224;
    const float* W; const float* b; ushort* Wb; float* bp; int N, K, KP;
    if (mat == 0)      { W = W0; b = b0; Wb = Wb0; bp = bp0; N = 200; K = 300; KP = 320; }
    else if (mat == 1) { W = W1; b = b1; Wb = Wb1; bp = bp1; N = 200; K = 200; KP = 224; }
    else if (mat == 2) { W = W2; b = b2; Wb = Wb2; bp = bp2; N = 200; K = 600; KP = 608; }
    else               { W = W3; b = b3; Wb = Wb3; bp = bp3; N = 200; K = 200; KP = 224; }
    for (int k = threadIdx.x; k < KP; k += 256)
        Wb[(size_t)n * KP + k] = (n < N && k < K) ? f2bf(W[(size_t)n * K + k]) : (ushort)0;
    if (threadIdx.x == 0) bp[n] = (n < N) ? b[n] : 0.f;
}

// ---------------------------------------------------------------------------
// sen f32 [8192][300] -> St bf16 [320][8192] transposed (pad rows zero).
// ---------------------------------------------------------------------------
__global__ __launch_bounds__(256) void transpose_bf16_kernel(
    const float* __restrict__ s1, const float* __restrict__ s2,
    ushort* __restrict__ St1, ushort* __restrict__ St2)
{
    const float* X = blockIdx.z ? s2 : s1;
    ushort* Xt = blockIdx.z ? St2 : St1;
    __shared__ float t[64][65];
    const int r0 = blockIdx.x * 64, c0 = blockIdx.y * 64;
    const int tc = threadIdx.x & 63, tr = threadIdx.x >> 6;
    for (int rr = tr; rr < 64; rr += 4) {
        int c = c0 + tc;
        t[rr][tc] = (c < 300) ? X[(size_t)(r0 + rr) * 300 + c] : 0.f;
    }
    __syncthreads();
    for (int rr = tr; rr < 64; rr += 4) {
        int oc = c0 + rr;
        if (oc < 320)
            Xt[(size_t)oc * 8192 + r0 + tc] = f2bf(t[tc][rr]);
    }
}

// ---------------------------------------------------------------------------
// Fused 2-layer MLP: Y = relu(relu(X@W1^T+b1)@W2^T+b2).
// X bf16 [M][KP1]; W1 [224][KP1]; W2 [224][224]; one wave, 16 rows/block.
// ---------------------------------------------------------------------------
__global__ __launch_bounds__(64) void mlp2_kernel(
    const ushort* __restrict__ X, int KP1,
    const ushort* __restrict__ W1, const float* __restrict__ b1,
    const ushort* __restrict__ W2, const float* __restrict__ b2,
    ushort* __restrict__ Ybf, float* __restrict__ Yf)
{
    const int r0 = blockIdx.x * 16;
    const int lane = threadIdx.x;
    const int lr = lane & 15, lg = lane >> 4;

    __shared__ __align__(16) ushort Y1[16][232];

    f32x4 a1[14];
#pragma unroll
    for (int t = 0; t < 14; ++t) a1[t] = f32x4{0.f, 0.f, 0.f, 0.f};

    const ushort* Xrow = X + (size_t)(r0 + lr) * KP1 + lg * 8;
    const ushort* W1r  = W1 + (size_t)lr * KP1 + lg * 8;
    for (int k0 = 0; k0 < KP1; k0 += 32) {
        short8 a = *(const short8*)(Xrow + k0);
#pragma unroll
        for (int t = 0; t < 14; ++t) {
            short8 bfr = *(const short8*)(W1r + (size_t)t * 16 * KP1 + k0);
            a1[t] = __builtin_amdgcn_mfma_f32_16x16x32_bf16(a, bfr, a1[t], 0, 0, 0);
        }
    }
#pragma unroll
    for (int t = 0; t < 14; ++t) {
        int col = t * 16 + lr;
        float bv = b1[col];
#pragma unroll
        for (int rr = 0; rr < 4; ++rr)
            Y1[lg * 4 + rr][col] = f2bf(fmaxf(a1[t][rr] + bv, 0.f));
    }
    __syncthreads();

    f32x4 a2[14];
#pragma unroll
    for (int t = 0; t < 14; ++t) a2[t] = f32x4{0.f, 0.f, 0.f, 0.f};
    const ushort* W2r = W2 + (size_t)lr * 224 + lg * 8;
    for (int k0 = 0; k0 < 224; k0 += 32) {
        short8 a = *(const short8*)&Y1[lr][lg * 8 + k0];
#pragma unroll
        for (int t = 0; t < 14; ++t) {
            short8 bfr = *(const short8*)(W2r + (size_t)t * 16 * 224 + k0);
            a2[t] = __builtin_amdgcn_mfma_f32_16x16x32_bf16(a, bfr, a2[t], 0, 0, 0);
        }
    }
#pragma unroll
    for (int t = 0; t < 14; ++t) {
        int col = t * 16 + lr;
        float bv = b2[col];
#pragma unroll
        for (int rr = 0; rr < 4; ++rr) {
            int row = r0 + lg * 4 + rr;
            float v = fmaxf(a2[t][rr] + bv, 0.f);
            if (Ybf) Ybf[(size_t)row * 224 + col] = f2bf(v);
            else if (col < 200) Yf[(size_t)row * 200 + col] = v;
        }
    }
}

// ---------------------------------------------------------------------------
// Flash attend, j-split, register-slim (target <=256 total regs/lane so the
// HW runs 2 waves/SIMD). 64 Q-rows x 4096 j per block, 4 waves, grid 512.
// E phase: wave w owns STRIP w (16 i-rows, A-frags in 28 regs, no cross-wave
//   duplication) x all 64 j; B tile staged per-iter into LDS in MFMA-fragment
//   layout (reg-staged: global loads issued early, ds_write after barrier).
// PV phase: wave w owns d-quarter [80w,80w+80) x all 64 i (as before).
// Block id: b = it + 128*jh + 256*dir so co-resident blocks share B/St in L2.
// ---------------------------------------------------------------------------
__global__ __launch_bounds__(256, 1) void attend_mfma_kernel(
    const ushort* __restrict__ FaFb, const ushort* __restrict__ St1,
    const ushort* __restrict__ St2, float* __restrict__ Pacc,
    float* __restrict__ Dpart)
{
    const int b = blockIdx.x;
    const int it  = b & 127;
    const int jh  = (b >> 7) & 1;
    const int dir = b >> 8;
    const ushort* A  = FaFb + (dir ? (size_t)8192 * 224 : 0);
    const ushort* B  = FaFb + (dir ? 0 : (size_t)8192 * 224);
    const ushort* St = dir ? St1 : St2;
    const int ib = it * 64;
    const int jo = jh * 4096;

    const int tid = threadIdx.x;
    const int w = tid >> 6;
    const int lane = tid & 63;
    const int lr = lane & 15, lg = lane >> 4;

    // B tile in MFMA-fragment layout: frag p = jt*7+kk; lane-linear 16B each.
    __shared__ __align__(16) ushort Bl[28 * 512];   // 28,672 B
    __shared__ __align__(16) ushort Pl[64][72];     //  9,216 B
    __shared__ float dled[4][64];                   //  1,024 B

    f32x4 acc[4][5];   // [i-strip][d-tile] PV accumulators
#pragma unroll
    for (int s = 0; s < 4; ++s)
#pragma unroll
        for (int t = 0; t < 5; ++t) acc[s][t] = f32x4{0.f, 0.f, 0.f, 0.f};
    float dsum[4] = {0.f, 0.f, 0.f, 0.f};

    // A fragments for THIS WAVE'S strip only: rows i = ib + w*16 + lr
    short8 afr[7];
    {
        const ushort* Ar = A + (size_t)(ib + w * 16 + lr) * 224 + lg * 8;
#pragma unroll
        for (int k = 0; k < 7; ++k) afr[k] = *(const short8*)(Ar + k * 32);
    }

    // B row this wave stages: j = jo + jb + w*16 + lr, cols q*32 + lg*8
    const ushort* Brow = B + (size_t)(jo + w * 16 + lr) * 224 + lg * 8;
    const ushort* Sbase = St + (size_t)(w * 80 + lr) * 8192 + jo + lg * 8;

    // prologue: stage B for jb=0
    {
        short8 bst[7];
#pragma unroll
        for (int q = 0; q < 7; ++q) bst[q] = *(const short8*)(Brow + q * 32);
#pragma unroll
        for (int q = 0; q < 7; ++q)
            *(short8*)&Bl[(w * 7 + q) * 512 + lane * 8] = bst[q];
    }
    __syncthreads();

    for (int jb = 0; jb < 4096; jb += 64) {
        // issue next-iter B loads early (latency hides under E)
        short8 bst[7];
        const bool more = (jb + 64 < 4096);
        if (more) {
#pragma unroll
            for (int q = 0; q < 7; ++q)
                bst[q] = *(const short8*)(Brow + (size_t)(jb + 64) * 224 + q * 32);
        }
        // issue St h0 loads (consumed in PV after barrier)
        short8 st0[5];
#pragma unroll
        for (int t = 0; t < 5; ++t)
            st0[t] = *(const short8*)(Sbase + (size_t)t * 16 * 8192 + jb);

        // ---- E: wave w computes E[strip w: 16 i x 64 j] from LDS B-frags --
        f32x4 e[4];
#pragma unroll
        for (int jt = 0; jt < 4; ++jt) e[jt] = f32x4{0.f, 0.f, 0.f, 0.f};
        short8 bf[4], bfn[4];
#pragma unroll
        for (int jt = 0; jt < 4; ++jt)
            bf[jt] = *(const short8*)&Bl[(jt * 7 + 0) * 512 + lane * 8];
#pragma unroll
        for (int kk = 0; kk < 7; ++kk) {
            if (kk < 6) {
#pragma unroll
                for (int jt = 0; jt < 4; ++jt)
                    bfn[jt] = *(const short8*)&Bl[(jt * 7 + kk + 1) * 512 + lane * 8];
            }
#pragma unroll
            for (int jt = 0; jt < 4; ++jt)
                e[jt] = __builtin_amdgcn_mfma_f32_16x16x32_bf16(afr[kk], bf[jt], e[jt], 0, 0, 0);
#pragma unroll
            for (int jt = 0; jt < 4; ++jt) bf[jt] = bfn[jt];
        }

        // exp (no max-sub: args ~2..5); in-lane j-sum; bf16 P -> LDS
        // e[jt] C-layout: col=lr (j in tile jt), row=lg*4+r (i in strip w)
#pragma unroll
        for (int jt = 0; jt < 4; ++jt)
#pragma unroll
            for (int r = 0; r < 4; ++r) {
                float x = __expf(e[jt][r]);
                dsum[r] += x;
                Pl[w * 16 + lg * 4 + r][jt * 16 + lr] = f2bf(x);
            }
        __syncthreads();   // Pl ready; Bl fully consumed

        // write next B frags into Bl (data arrived during E)
        if (more) {
#pragma unroll
            for (int q = 0; q < 7; ++q)
                *(short8*)&Bl[(w * 7 + q) * 512 + lane * 8] = bst[q];
        }
        // issue St h1 loads (consumed in PV h1, hides under h0 compute)
        short8 st1[5];
#pragma unroll
        for (int t = 0; t < 5; ++t)
            st1[t] = *(const short8*)(Sbase + (size_t)t * 16 * 8192 + jb + 32);

        // ---- PV: wave w computes O[64 i x 80 d] over these 64 j ----
        {
            short8 pf[4];
#pragma unroll
            for (int s = 0; s < 4; ++s)
                pf[s] = *(const short8*)&Pl[s * 16 + lr][lg * 8];
#pragma unroll
            for (int s = 0; s < 4; ++s)
#pragma unroll
                for (int t = 0; t < 5; ++t)
                    acc[s][t] = __builtin_amdgcn_mfma_f32_16x16x32_bf16(pf[s], st0[t], acc[s][t], 0, 0, 0);
        }
        {
            short8 pf[4];
#pragma unroll
            for (int s = 0; s < 4; ++s)
                pf[s] = *(const short8*)&Pl[s * 16 + lr][32 + lg * 8];
#pragma unroll
            for (int s = 0; s < 4; ++s)
#pragma unroll
                for (int t = 0; t < 5; ++t)
                    acc[s][t] = __builtin_amdgcn_mfma_f32_16x16x32_bf16(pf[s], st1[t], acc[s][t], 0, 0, 0);
        }
        __syncthreads();   // Pl consumed; Bl writes visible for next E
    }

    // denominator: each wave has FULL j-range sums for its strip's rows.
    // reduce over the 16 lr lanes (j within tile), rows i = w*16 + lg*4 + r
#pragma unroll
    for (int m = 1; m < 16; m <<= 1)
#pragma unroll
        for (int r = 0; r < 4; ++r)
            dsum[r] += __shfl_xor(dsum[r], m);
    if (lr == 0) {
#pragma unroll
        for (int r = 0; r < 4; ++r)
            dled[w][lg * 4 + r] = dsum[r];
    }
    __syncthreads();

    // Dpart[jh][dir*8192 + ib + il]
    if (tid < 64)
        Dpart[(size_t)jh * 16384 + dir * 8192 + ib + tid] = dled[tid >> 4][tid & 15];

    // raw partials: Pacc[jh][dir*8192 + i][d]
    float* Pb = Pacc + ((size_t)jh * 16384 + dir * 8192 + ib) * 320;
#pragma unroll
    for (int t = 0; t < 5; ++t) {
        int d = w * 80 + t * 16 + lr;
#pragma unroll
        for (int s = 0; s < 4; ++s)
#pragma unroll
            for (int r = 0; r < 4; ++r)
                Pb[(size_t)(s * 16 + lg * 4 + r) * 320 + d] = acc[s][t][r];
    }
}

// ---------------------------------------------------------------------------
// combine: beta/alpha = (PaccA + PaccB) / (DA + DB) -> bf16 into Xcat[.,300+]
// ---------------------------------------------------------------------------
__global__ __launch_bounds__(256) void combine_kernel(
    const float* __restrict__ Pacc, const float* __restrict__ Dpart,
    ushort* __restrict__ Xcat)
{
    const int row = blockIdx.x * 8 + (threadIdx.x >> 5);
    const int c0 = threadIdx.x & 31;
    const float inv = 1.f / (Dpart[row] + Dpart[16384 + row]);
    const float* pa = Pacc + (size_t)row * 320;
    const float* pb = Pacc + (size_t)(16384 + row) * 320;
    ushort* xc = Xcat + (size_t)row * 608 + 300;
    for (int d = c0; d < 300; d += 32)
        xc[d] = f2bf((pa[d] + pb[d]) * inv);
}

// ---------------------------------------------------------------------------
// hsum[c] = sum_r v[r][c%200] over the half selected by c/200. c in [0,400).
// ---------------------------------------------------------------------------
__global__ __launch_bounds__(256) void colsum_kernel(
    const float* __restrict__ v, float* __restrict__ hsum)
{
    const int c = blockIdx.x;
    const float* V = v + (c < 200 ? 0 : (size_t)8192 * 200);
    const int col = c % 200;
    float s = 0.f;
    for (int r = threadIdx.x; r < 8192; r += 256)
        s += V[(size_t)r * 200 + col];
    __shared__ float red[256];
    red[threadIdx.x] = s;
    __syncthreads();
    for (int off = 128; off > 0; off >>= 1) {
        if (threadIdx.x < off) red[threadIdx.x] += red[threadIdx.x + off];
        __syncthreads();
    }
    if (threadIdx.x == 0) hsum[c] = red[0];
}

__global__ __launch_bounds__(256) void head_kernel(
    const float* __restrict__ hsum,
    const float* __restrict__ Hw1, const float* __restrict__ Hb1,
    const float* __restrict__ Hw2, const float* __restrict__ Hb2,
    float* __restrict__ out)
{
    __shared__ float hx[400];
    __shared__ float hr[200];
    __shared__ float lg[3];
    const int t = threadIdx.x;
    for (int i = t; i < 400; i += 256) hx[i] = hsum[i];
    __syncthreads();
    if (t < 200) {
        float a = Hb1[t];
        for (int k = 0; k < 400; ++k) a = fmaf(hx[k], Hw1[t * 400 + k], a);
        hr[t] = fmaxf(a, 0.f);
    }
    __syncthreads();
    if (t < 3) {
        float a = Hb2[t];
        for (int k = 0; k < 200; ++k) a = fmaf(hr[k], Hw2[t * 200 + k], a);
        lg[t] = a;
    }
    __syncthreads();
    if (t == 0) {
        float m = fmaxf(lg[0], fmaxf(lg[1], lg[2]));
        float e0 = __expf(lg[0] - m);
        float e1 = __expf(lg[1] - m);
        float e2 = __expf(lg[2] - m);
        float s = e0 + e1 + e2;
        out[0] = e0 / s;
        out[1] = e1 / s;
        out[2] = e2 / s;
    }
}

extern "C" void kernel_launch(void* const* d_in, const int* in_sizes, int n_in,
                              void* d_out, int out_size, void* d_ws, size_t ws_size,
                              hipStream_t stream)
{
    const float* sen1 = (const float*)d_in[0];
    const float* sen2 = (const float*)d_in[1];
    const float* F_w1 = (const float*)d_in[2];
    const float* F_b1 = (const float*)d_in[3];
    const float* F_w2 = (const float*)d_in[4];
    const float* F_b2 = (const float*)d_in[5];
    const float* G_w1 = (const float*)d_in[6];
    const float* G_b1 = (const float*)d_in[7];
    const float* G_w2 = (const float*)d_in[8];
    const float* G_b2 = (const float*)d_in[9];
    const float* H_w1 = (const float*)d_in[10];
    const float* H_b1 = (const float*)d_in[11];
    const float* H_w2 = (const float*)d_in[12];
    const float* H_b2 = (const float*)d_in[13];
    float* out = (float*)d_out;

    const int L = 8192;
    char* p = (char*)d_ws;
    ushort* St1  = (ushort*)p; p += (size_t)320 * L * 2;       // 5.24 MB
    ushort* St2  = (ushort*)p; p += (size_t)320 * L * 2;       // 5.24 MB
    ushort* FaFb = (ushort*)p; p += (size_t)2 * L * 224 * 2;   // 7.34 MB
    ushort* Xcat = (ushort*)p; p += (size_t)2 * L * 608 * 2;   // 19.92 MB
    ushort* WbF1 = (ushort*)p; p += (size_t)224 * 320 * 2;
    ushort* WbF2 = (ushort*)p; p += (size_t)224 * 224 * 2;
    ushort* WbG1 = (ushort*)p; p += (size_t)224 * 608 * 2;
    ushort* WbG2 = (ushort*)p; p += (size_t)224 * 224 * 2;
    float*  bpF1 = (float*)p;  p += 224 * 4;
    float*  bpF2 = (float*)p;  p += 224 * 4;
    float*  bpG1 = (float*)p;  p += 224 * 4;
    float*  bpG2 = (float*)p;  p += 224 * 4;
    float*  hsum = (float*)p;  p += 400 * 4;
    // union region U: Senb (10.5 MB, pre-attend) / Pacc+Dpart (42.1 MB,
    // attend+combine) / v (26.2 MB, post-combine)
    ushort* Senb  = (ushort*)p;
    float*  Pacc  = (float*)p;
    float*  Dpart = (float*)(p + (size_t)2 * 16384 * 320 * 4);
    float*  v     = (float*)p;

    dim3 blk256(256);

    hipLaunchKernelGGL(convert_inputs_kernel, dim3(2 * L / 8), blk256, 0, stream,
                       sen1, sen2, Senb, Xcat);
    hipLaunchKernelGGL(transpose_bf16_kernel, dim3(L / 64, 5, 2), blk256, 0, stream,
                       sen1, sen2, St1, St2);
    hipLaunchKernelGGL(convert_weights_kernel, dim3(4 * 224), blk256, 0, stream,
                       F_w1, F_b1, F_w2, F_b2, G_w1, G_b1, G_w2, G_b2,
                       WbF1, bpF1, WbF2, bpF2, WbG1, bpG1, WbG2, bpG2);

    // F MLP fused (both sentences, M = 16384) -> FaFb bf16
    hipLaunchKernelGGL(mlp2_kernel, dim3(2 * L / 16), dim3(64), 0, stream,
                       Senb, 320, WbF1, bpF1, WbF2, bpF2, FaFb, (float*)nullptr);

    // flash attend, j-split partials
    hipLaunchKernelGGL(attend_mfma_kernel, dim3(512), blk256, 0, stream,
                       FaFb, St1, St2, Pacc, Dpart);
    // combine -> Xcat cols 300..599
    hipLaunchKernelGGL(combine_kernel, dim3(16384 / 8), blk256, 0, stream,
                       Pacc, Dpart, Xcat);

    // G MLP fused -> v f32
    hipLaunchKernelGGL(mlp2_kernel, dim3(2 * L / 16), dim3(64), 0, stream,
                       Xcat, 608, WbG1, bpG1, WbG2, bpG2, (ushort*)nullptr, v);

    hipLaunchKernelGGL(colsum_kernel, dim3(400), blk256, 0, stream, v, hsum);
    hipLaunchKernelGGL(head_kernel, dim3(1), blk256, 0, stream,
                       hsum, H_w1, H_b1, H_w2, H_b2, out);
}